// Round 8
// baseline (236.819 us; speedup 1.0000x reference)
//
#include <hip/hip_runtime.h>

#define BSZ   4096
#define LSEQ  50
#define KFR   10
#define LI    20
#define DIM   64
#define NITEM 50001   // NI+1
#define CCLS  10

typedef __attribute__((ext_vector_type(8))) short short8;
typedef __attribute__((ext_vector_type(4))) float floatx4;

#define LOG2E 1.442695040888963f

__device__ inline unsigned short f2bf(float f) {
  unsigned u = __builtin_bit_cast(unsigned, f);
  u += 0x7FFF + ((u >> 16) & 1);
  return (unsigned short)(u >> 16);
}
__device__ inline float bf2f(unsigned short u) {
  return __builtin_bit_cast(float, ((unsigned)u) << 16);
}
__device__ inline float fast_exp(float x) {
  return __builtin_amdgcn_exp2f(x * LOG2E);
}
__device__ inline float fast_sigmoid(float x) {
  float e = __builtin_amdgcn_exp2f(-LOG2E * x);
  return __builtin_amdgcn_rcpf(1.0f + e);
}
__device__ inline float fast_tanh(float x) {
  float e = __builtin_amdgcn_exp2f(2.0f * LOG2E * x);
  return 1.0f - 2.0f * __builtin_amdgcn_rcpf(e + 1.0f);
}

// ---------------------------------------------------------------------------
// item_transform body (MFMA) + gxi phase.
// Phase 1 (unchanged): ju = [emb|cls]@W1+b1, jv = [emb|cls]@W3+b3 (bf16 out).
// Phase 2 (new): gxi = ju @ Wih + (bih+bhh)  — hoists the non-recurrent half
// of the LSTM gate GEMM out of the D2 serial chain. ju tile is transposed
// within-wave via a small LDS scratch (same wave wrote it -> lgkm-ordered,
// no barrier); Wih is staged once per block in LDS (transposed + swizzled).
// ---------------------------------------------------------------------------
__device__ __forceinline__ void item_block(int bid, int nblk,
                                 const float* __restrict__ item_emb,
                                 const float* __restrict__ i_class,
                                 const float* __restrict__ W1, const float* __restrict__ b1,
                                 const float* __restrict__ W3, const float* __restrict__ b3,
                                 const float* __restrict__ Wih,
                                 const float* __restrict__ bih, const float* __restrict__ bhh,
                                 unsigned short* __restrict__ ju_all,
                                 unsigned short* __restrict__ jv_all,
                                 unsigned short* __restrict__ gxi) {
  __shared__ float wcls[2][CCLS][64];
  __shared__ unsigned short wihT[256 * 64];         // Wih^T, chunk-swizzled
  __shared__ unsigned short jt[4][16 * 64];         // per-wave ju-tile scratch

  for (int i = threadIdx.x; i < CCLS * 64; i += 256) {
    wcls[0][i >> 6][i & 63] = W1[(64 + (i >> 6)) * 64 + (i & 63)];
    wcls[1][i >> 6][i & 63] = W3[(64 + (i >> 6)) * 64 + (i & 63)];
  }
  // stage Wih transposed: wihT[n][swz(k)] = Wih[k][n]
  for (int idx = threadIdx.x; idx < 64 * 256; idx += 256) {
    int k = idx >> 8, n = idx & 255;
    wihT[n * 64 + (((k >> 3) ^ (n & 7)) << 3) + (k & 7)] = f2bf(Wih[k * 256 + n]);
  }
  __syncthreads();
  const int lane = threadIdx.x & 63;
  const int w = threadIdx.x >> 6;
  const int am = lane & 15, aq = lane >> 4;

  short8 bf[2][4][2];
  #pragma unroll
  for (int t = 0; t < 4; t++) {
    #pragma unroll
    for (int f = 0; f < 2; f++) {
      short8 v1, v3;
      #pragma unroll
      for (int j = 0; j < 8; j++) {
        int k = f * 32 + aq * 8 + j;
        int n = t * 16 + am;
        v1[j] = (short)f2bf(W1[k * 64 + n]);
        v3[j] = (short)f2bf(W3[k * 64 + n]);
      }
      bf[0][t][f] = v1; bf[1][t][f] = v3;
    }
  }
  float bias1[4], bias3[4];
  #pragma unroll
  for (int t = 0; t < 4; t++) { bias1[t] = b1[t * 16 + am]; bias3[t] = b3[t * 16 + am]; }
  // per-n gate bias (bih+bhh), n = t2*16+am
  float bs2[16];
  #pragma unroll
  for (int t2 = 0; t2 < 16; t2++) {
    int n = t2 * 16 + am;
    bs2[t2] = bih[n] + bhh[n];
  }

  const int gw = (bid * 256 + threadIdx.x) >> 6;
  const int nw = nblk * 4;
  const int ntiles = (NITEM + 15) / 16;
  for (int tile = gw; tile < ntiles; tile += nw) {
    const int r0 = tile * 16;
    const int row_a = r0 + am;
    const bool va = row_a < NITEM;
    short8 af[2];
    #pragma unroll
    for (int f = 0; f < 2; f++) {
      short8 v = {0, 0, 0, 0, 0, 0, 0, 0};
      if (va) {
        const float* p = item_emb + row_a * 64 + f * 32 + aq * 8;
        #pragma unroll
        for (int j = 0; j < 8; j++) v[j] = (short)f2bf(p[j]);
      }
      af[f] = v;
    }
    float cf = 0.f;
    if (va) {
      #pragma unroll
      for (int j = 1; j < CCLS; j++) cf += i_class[row_a * CCLS + j] * (float)j;
    }
    int ci_l = (int)(cf + 0.5f);

    floatx4 acc[2][4];
    #pragma unroll
    for (int mt = 0; mt < 2; mt++)
      #pragma unroll
      for (int t = 0; t < 4; t++) {
        floatx4 a = {0.f, 0.f, 0.f, 0.f};
        a = __builtin_amdgcn_mfma_f32_16x16x32_bf16(af[0], bf[mt][t][0], a, 0, 0, 0);
        a = __builtin_amdgcn_mfma_f32_16x16x32_bf16(af[1], bf[mt][t][1], a, 0, 0, 0);
        acc[mt][t] = a;
      }
    #pragma unroll
    for (int r = 0; r < 4; r++) {
      int row = aq * 4 + r;
      int grow = r0 + row;
      int ci = __shfl(ci_l, row, 64);
      if (grow < NITEM) {
        #pragma unroll
        for (int t = 0; t < 4; t++) {
          int n = t * 16 + am;
          unsigned short jb = f2bf(acc[0][t][r] + wcls[0][ci][n] + bias1[t]);
          ju_all[grow * 64 + n] = jb;
          jv_all[grow * 64 + n] = f2bf(acc[1][t][r] + wcls[1][ci][n] + bias3[t]);
          // also drop ju into per-wave LDS scratch (swizzled) for transpose
          jt[w][row * 64 + (((n >> 3) ^ (row & 7)) << 3) + (n & 7)] = jb;
        }
      } else {
        #pragma unroll
        for (int t = 0; t < 4; t++) {
          int n = t * 16 + am;
          jt[w][row * 64 + (((n >> 3) ^ (row & 7)) << 3) + (n & 7)] = 0;
        }
      }
    }
    // ---- phase 2: gxi tile = ju_tile @ Wih + (bih+bhh)
    // same-wave ds_write -> ds_read: lgkmcnt-ordered, no barrier needed.
    short8 aj[2];
    #pragma unroll
    for (int f = 0; f < 2; f++) {
      int chunk = (f * 4 + aq) ^ (am & 7);
      aj[f] = *(const short8*)&jt[w][am * 64 + chunk * 8];
    }
    #pragma unroll
    for (int t2 = 0; t2 < 16; t2++) {
      const int n = t2 * 16 + am;
      short8 bw[2];
      #pragma unroll
      for (int f = 0; f < 2; f++) {
        int chunk = (f * 4 + aq) ^ (n & 7);
        bw[f] = *(const short8*)&wihT[n * 64 + chunk * 8];
      }
      floatx4 a2 = {0.f, 0.f, 0.f, 0.f};
      a2 = __builtin_amdgcn_mfma_f32_16x16x32_bf16(aj[0], bw[0], a2, 0, 0, 0);
      a2 = __builtin_amdgcn_mfma_f32_16x16x32_bf16(aj[1], bw[1], a2, 0, 0, 0);
      #pragma unroll
      for (int r = 0; r < 4; r++) {
        int grow = r0 + aq * 4 + r;
        if (grow < NITEM)
          gxi[(size_t)grow * 256 + n] = f2bf(a2[r] + bs2[t2]);
      }
    }
  }
}

// ---------------------------------------------------------------------------
// social DOTS body: s1/s2 scores -> s12T, attention weights -> auv.
// ---------------------------------------------------------------------------
__device__ __forceinline__ void social_dots_block(int bid,
                         const int* __restrict__ users, const int* __restrict__ u_frids,
                         const int* __restrict__ u_frids_mask,
                         const float* __restrict__ user_emb,
                         const float* __restrict__ W4, const float* __restrict__ b4,
                         const int* __restrict__ items, const float* __restrict__ item_emb,
                         const int* __restrict__ F_i, const float* __restrict__ W6,
                         const float* __restrict__ b6,
                         float* __restrict__ auv, float* __restrict__ s12T) {
  const int b = (bid * 256 + threadIdx.x) >> 6;
  if (b >= BSZ) return;
  const int lane = threadIdx.x & 63;

  float w4a = W4[lane], w4b = W4[64 + lane];
  float w6a = W6[lane], w6b = W6[64 + lane];
  float p[32];
  p[0] = user_emb[users[b] * 64 + lane] * w4a;
  p[1] = item_emb[items[b] * 64 + lane] * w6a;
  #pragma unroll
  for (int k = 0; k < KFR; k++)
    p[2 + k] = user_emb[u_frids[b * KFR + k] * 64 + lane] * w4b;
  #pragma unroll
  for (int k = 0; k < KFR; k++) {
    p[12 + k] = item_emb[F_i[b * 2 * KFR + k] * 64 + lane] * w6b;
    p[22 + k] = item_emb[F_i[b * 2 * KFR + KFR + k] * 64 + lane] * w6b;
  }
  #pragma unroll
  for (int off = 1; off < 64; off <<= 1) {
    #pragma unroll
    for (int i = 0; i < 32; i++) p[i] += __shfl_xor(p[i], off, 64);
  }

  float du = p[0] + b4[0];
  float di = p[1] + b6[0];
  int km = u_frids_mask[b];
  float at[KFR];
  float M = -1e30f;
  #pragma unroll
  for (int k = 0; k < KFR; k++) {
    float s = p[2 + k] + du;
    at[k] = (s > 0.f) ? s : 0.01f * s;
    if (k < km) M = fmaxf(M, at[k]);
  }
  float E = 0.f;
  #pragma unroll
  for (int k = 0; k < KFR; k++) {
    at[k] = (k < km) ? fast_exp(at[k] - M) : 0.f;
    E += at[k];
  }
  float scale = __builtin_amdgcn_rcpf(E) * __builtin_amdgcn_rcpf((float)km);
  if (lane == 0) {
    #pragma unroll
    for (int k = 0; k < KFR; k++) {
      auv[b * KFR + k] = at[k] * scale;
      float r1 = p[12 + k] + di; r1 = (r1 > 0.f) ? r1 : 0.01f * r1;
      float r2 = p[22 + k] + di; r2 = (r2 > 0.f) ? r2 : 0.01f * r2;
      s12T[k * BSZ + b] = r1;
      s12T[(KFR + k) * BSZ + b] = r2;
    }
  }
}

// ---------------------------------------------------------------------------
// D1 kernel: blocks 0..1023 item_transform(+gxi); 1024..2047 social dots.
// ---------------------------------------------------------------------------
__launch_bounds__(256, 1)
__global__ void k_item_dots(const float* __restrict__ item_emb,
                            const float* __restrict__ i_class,
                            const float* __restrict__ W1, const float* __restrict__ b1,
                            const float* __restrict__ W3, const float* __restrict__ b3,
                            const float* __restrict__ Wih,
                            const float* __restrict__ bih, const float* __restrict__ bhh,
                            unsigned short* __restrict__ ju_all,
                            unsigned short* __restrict__ jv_all,
                            unsigned short* __restrict__ gxi,
                            const int* __restrict__ users, const int* __restrict__ u_frids,
                            const int* __restrict__ u_frids_mask,
                            const float* __restrict__ user_emb,
                            const float* __restrict__ W4, const float* __restrict__ b4,
                            const int* __restrict__ items,
                            const int* __restrict__ F_i, const float* __restrict__ W6,
                            const float* __restrict__ b6,
                            float* __restrict__ auv, float* __restrict__ s12T) {
  if (blockIdx.x < 1024) {
    item_block(blockIdx.x, 1024, item_emb, i_class, W1, b1, W3, b3, Wih, bih, bhh,
               ju_all, jv_all, gxi);
  } else {
    social_dots_block(blockIdx.x - 1024, users, u_frids, u_frids_mask, user_emb, W4, b4,
                      items, item_emb, F_i, W6, b6, auv, s12T);
  }
}

// ---------------------------------------------------------------------------
// LSTM block body — gxi-fed variant of the proven R4 config.
// 256 blocks x 16 rows x 4 waves; per step only the RECURRENT half of the
// gate GEMM runs: 8 MFMAs (K=64, 2-deep chain) vs 16 (4-deep) before.
// x never staged (no xw loads / LDS writes); gate x-part+biases arrive via
// gxi gather, prefetched one full step ahead (latency-free). xh keeps the
// R4 geometry/swizzle exactly (h in chunks 8..15) -> 0 bank conflicts.
// ---------------------------------------------------------------------------
__device__ __forceinline__ void lstm_block(int bid,
                       const unsigned short* __restrict__ gxi,
                       const int* __restrict__ u_items,
                       const int* __restrict__ u_items_mask,
                       const float* __restrict__ Whh,
                       float* __restrict__ hu) {
  __shared__ __attribute__((aligned(16))) unsigned short xh[2][16 * 128];
  __shared__ int uidx[16][LSEQ];

  const int tid = threadIdx.x;
  const int lane = tid & 63;
  const int w = tid >> 6;
  const int b0 = bid * 16;
  const int am = lane & 15;
  const int aq = lane >> 4;
  const int dcol = w * 16 + am;

  // Whh B-frags: gate g, recurrent k = f*32 + aq*8 + j (f = 0,1 -> Whh rows)
  short8 bfrag[4][2];
  #pragma unroll
  for (int g = 0; g < 4; g++) {
    const int ncol = g * 64 + dcol;
    #pragma unroll
    for (int f = 0; f < 2; f++) {
      short8 vv;
      #pragma unroll
      for (int j = 0; j < 8; j++) {
        int kh = f * 32 + aq * 8 + j;
        vv[j] = (short)f2bf(Whh[kh * 256 + ncol]);
      }
      bfrag[g][f] = vv;
    }
  }
  for (int idx = tid; idx < 16 * LSEQ; idx += 256) {
    int m = idx / LSEQ, l = idx % LSEQ;
    uidx[m][l] = u_items[(b0 + m) * LSEQ + l];
  }
  __syncthreads();   // uidx ready

  float cst[4] = {0.f, 0.f, 0.f, 0.f};
  int maskr[4];
  #pragma unroll
  for (int r = 0; r < 4; r++) maskr[r] = u_items_mask[b0 + aq * 4 + r];

  // zero h region of xh[0] (cols 64..127 of the R4 layout)
  {
    const int j = lane;
    #pragma unroll
    for (int i = 0; i < 4; i++) {
      int m = w + i * 4;
      int k2 = 64 + j;
      xh[0][m * 128 + (((k2 >> 3) ^ m) << 3) + (k2 & 7)] = 0;
    }
  }
  // gx for step 0
  unsigned short gxc[4][4];   // [g][r]
  #pragma unroll
  for (int r = 0; r < 4; r++) {
    int m = aq * 4 + r;
    const unsigned short* gp = gxi + (size_t)uidx[m][0] * 256;
    #pragma unroll
    for (int g = 0; g < 4; g++) gxc[g][r] = gp[g * 64 + dcol];
  }
  __syncthreads();   // xh[0] ready

  #pragma unroll 1
  for (int l = 0; l < LSEQ; l++) {
    const int p = l & 1, q = 1 - p;
    // prefetch next step's gx (16 scalar bf16 loads, a full step to land)
    unsigned short gxn[4][4];
    if (l < LSEQ - 1) {
      #pragma unroll
      for (int r = 0; r < 4; r++) {
        int m = aq * 4 + r;
        const unsigned short* gp = gxi + (size_t)uidx[m][l + 1] * 256;
        #pragma unroll
        for (int g = 0; g < 4; g++) gxn[g][r] = gp[g * 64 + dcol];
      }
    }
    short8 af[2];
    #pragma unroll
    for (int f = 0; f < 2; f++) {
      int chunk = (4 * (f + 2) + aq) ^ am;     // h chunks 8..15, R4-identical
      af[f] = *(const short8*)&xh[p][am * 128 + chunk * 8];
    }
    floatx4 acc[4];
    #pragma unroll
    for (int g = 0; g < 4; g++) {
      floatx4 a = {bf2f(gxc[g][0]), bf2f(gxc[g][1]), bf2f(gxc[g][2]), bf2f(gxc[g][3])};
      a = __builtin_amdgcn_mfma_f32_16x16x32_bf16(af[0], bfrag[g][0], a, 0, 0, 0);
      a = __builtin_amdgcn_mfma_f32_16x16x32_bf16(af[1], bfrag[g][1], a, 0, 0, 0);
      acc[g] = a;
    }
    const int kcol = 64 + dcol;
    #pragma unroll
    for (int r = 0; r < 4; r++) {
      float gi = acc[0][r];
      float gf = acc[1][r];
      float gg = acc[2][r];
      float go = acc[3][r];
      float c = fast_sigmoid(gf) * cst[r] + fast_sigmoid(gi) * fast_tanh(gg);
      cst[r] = c;
      float h = fast_sigmoid(go) * fast_tanh(c);
      int m = aq * 4 + r;
      if (l == maskr[r] - 1) hu[(b0 + m) * 64 + dcol] = h;
      xh[q][m * 128 + (((kcol >> 3) ^ m) << 3) + (kcol & 7)] = f2bf(h);
    }
    if (l < LSEQ - 1) {
      #pragma unroll
      for (int g = 0; g < 4; g++)
        #pragma unroll
        for (int r = 0; r < 4; r++) gxc[g][r] = gxn[g][r];
    }
    __syncthreads();
  }
}

// ---------------------------------------------------------------------------
// social PV body: gather 200 jv rows, weighted-sum with precomputed auv -> su.
// ---------------------------------------------------------------------------
__device__ __forceinline__ void social_pv_block(int bid,
                         const int* __restrict__ u_frids_items,
                         const unsigned short* __restrict__ jv_all,
                         const float* __restrict__ auv,
                         float* __restrict__ su) {
  const int b = (bid * 256 + threadIdx.x) >> 6;
  if (b >= BSZ) return;
  const int lane = threadIdx.x & 63;

  const int* fit = u_frids_items + b * (KFR * LI);
  int idx0 = fit[lane];
  int idx1 = fit[64 + lane];
  int idx2 = fit[128 + lane];
  int idx3 = (lane < 8) ? fit[192 + lane] : 0;

  float s = 0.f;
  #pragma unroll
  for (int k = 0; k < KFR; k++) {
    float a = auv[b * KFR + k];
    float pk = 0.f;
    #pragma unroll
    for (int li = 0; li < LI; li++) {
      int j = k * LI + li;
      int idx;
      if (j < 64)       idx = __shfl(idx0, j, 64);
      else if (j < 128) idx = __shfl(idx1, j - 64, 64);
      else if (j < 192) idx = __shfl(idx2, j - 128, 64);
      else              idx = __shfl(idx3, j - 192, 64);
      pk += bf2f(jv_all[idx * 64 + lane]);
    }
    s = fmaf(a, pk, s);
  }
  su[b * 64 + lane] = s;
}

// ---------------------------------------------------------------------------
// colstats body: softmax stats for one column.
// ---------------------------------------------------------------------------
__device__ __forceinline__ void colstats_block(int c,
                         const float* __restrict__ s12T, float* __restrict__ stats) {
  __shared__ float red[256];
  const float* col = s12T + c * BSZ;
  float m = -1e30f;
  for (int b = threadIdx.x; b < BSZ; b += 256) m = fmaxf(m, col[b]);
  red[threadIdx.x] = m;
  __syncthreads();
  for (int s = 128; s > 0; s >>= 1) {
    if (threadIdx.x < s) red[threadIdx.x] = fmaxf(red[threadIdx.x], red[threadIdx.x + s]);
    __syncthreads();
  }
  float M = red[0];
  __syncthreads();
  float e = 0.f;
  for (int b = threadIdx.x; b < BSZ; b += 256) e += fast_exp(col[b] - M);
  red[threadIdx.x] = e;
  __syncthreads();
  for (int s = 128; s > 0; s >>= 1) {
    if (threadIdx.x < s) red[threadIdx.x] += red[threadIdx.x + s];
    __syncthreads();
  }
  if (threadIdx.x == 0) { stats[c] = M; stats[20 + c] = red[0]; }
}

// ---------------------------------------------------------------------------
// D2 kernel: blocks 0..255 LSTM; 256..1279 social pv; 1280..1299 colstats.
// ---------------------------------------------------------------------------
__launch_bounds__(256, 1)
__global__ void k_lstm_pv(const unsigned short* __restrict__ gxi,
                          const int* __restrict__ u_items,
                          const int* __restrict__ u_items_mask,
                          const float* __restrict__ Whh,
                          float* __restrict__ hu,
                          const int* __restrict__ u_frids_items,
                          const unsigned short* __restrict__ jv_all,
                          const float* __restrict__ auv, float* __restrict__ su,
                          const float* __restrict__ s12T, float* __restrict__ stats) {
  if (blockIdx.x < 256) {
    lstm_block(blockIdx.x, gxi, u_items, u_items_mask, Whh, hu);
  } else if (blockIdx.x < 1280) {
    social_pv_block(blockIdx.x - 256, u_frids_items, jv_all, auv, su);
  } else {
    colstats_block(blockIdx.x - 1280, s12T, stats);
  }
}

// ---------------------------------------------------------------------------
// D3 (MFMA): hui/sui GEMMs + final epilogue, 16-row tiles, GEMM/gather
// wave split (waves 0-3 GEMM, waves 4-7 yi gather concurrently).
// ---------------------------------------------------------------------------
__launch_bounds__(512, 1)
__global__ void k_fuse_final(const float* __restrict__ hu, const float* __restrict__ su,
                             const int* __restrict__ items,
                             const float* __restrict__ item_emb,
                             const float* __restrict__ W2, const float* __restrict__ b2,
                             const float* __restrict__ W5, const float* __restrict__ b5,
                             const int* __restrict__ F_i,
                             const float* __restrict__ s12T, const float* __restrict__ stats,
                             const float* __restrict__ alpha, const float* __restrict__ lambdas,
                             float* __restrict__ out) {
  __shared__ float huis[16][66];
  __shared__ float suis[16][66];

  const int lane = threadIdx.x & 63;
  const int w = threadIdx.x >> 6;      // 0..7
  const int r0 = blockIdx.x * 16;

  const float al = alpha[0];
  const float l0 = lambdas[0], l1 = lambdas[1], l2 = lambdas[2], l3 = lambdas[3];

  float yi_r[4];
  float tp_r[4];

  if (w < 4) {
    const int mat = w >> 1;
    const int half = w & 1;
    const int am = lane & 15, aq = lane >> 4;

    const float* W = mat ? W5 : W2;
    const float* bb = mat ? b5 : b2;
    const float* xsrc = mat ? su : hu;

    short8 bfr[6][2];
    #pragma unroll
    for (int f = 0; f < 6; f++) {
      #pragma unroll
      for (int t = 0; t < 2; t++) {
        const int n = half * 32 + t * 16 + am;
        short8 v;
        #pragma unroll
        for (int j = 0; j < 8; j++) {
          int k = f * 32 + aq * 8 + j;
          v[j] = (short)f2bf(W[k * 64 + n]);
        }
        bfr[f][t] = v;
      }
    }
    float bias[2];
    #pragma unroll
    for (int t = 0; t < 2; t++) bias[t] = bb[half * 32 + t * 16 + am];

    const int row_a = r0 + am;
    const int it = items[row_a];
    short8 af[6];
    #pragma unroll
    for (int c = 0; c < 2; c++) {
      short8 vx, ve, vp;
      const float* xp = xsrc + row_a * 64 + c * 32 + aq * 8;
      const float* ep = item_emb + it * 64 + c * 32 + aq * 8;
      #pragma unroll
      for (int j = 0; j < 8; j++) {
        float x = xp[j], e = ep[j];
        vx[j] = (short)f2bf(x);
        ve[j] = (short)f2bf(e);
        vp[j] = (short)f2bf(x * e);
      }
      af[c] = vx; af[2 + c] = ve; af[4 + c] = vp;
    }
    floatx4 acc[2];
    #pragma unroll
    for (int t = 0; t < 2; t++) {
      floatx4 a = {0.f, 0.f, 0.f, 0.f};
      #pragma unroll
      for (int f = 0; f < 6; f++)
        a = __builtin_amdgcn_mfma_f32_16x16x32_bf16(af[f], bfr[f][t], a, 0, 0, 0);
      acc[t] = a;
    }
    float (*dst)[66] = mat ? suis : huis;
    #pragma unroll
    for (int t = 0; t < 2; t++)
      #pragma unroll
      for (int r = 0; r < 4; r++)
        dst[aq * 4 + r][half * 32 + t * 16 + am] = acc[t][r] + bias[t];
  } else {
    #pragma unroll
    for (int rr = 0; rr < 4; rr++) {
      const int r = r0 + (w - 4) * 4 + rr;
      float p1 = 0.f, p2 = 0.f;
      if (lane < KFR) {
        float v1 = s12T[lane * BSZ + r];
        float v2 = s12T[(KFR + lane) * BSZ + r];
        p1 = fast_exp(v1 - stats[lane]) * __builtin_amdgcn_rcpf(stats[20 + lane]);
        p2 = fast_exp(v2 - stats[KFR + lane]) * __builtin_amdgcn_rcpf(stats[30 + lane]);
      }
      float yi = 0.f;
      #pragma unroll
      for (int k = 0; k < KFR; k++) {
        float a1 = __shfl(p1, k, 64);
        float a2 = __shfl(p2, k, 64);
        int i1 = F_i[r * 2 * KFR + k];
        int i2 = F_i[r * 2 * KFR + KFR + k];
        yi += al * a1 * item_emb[i1 * 64 + lane] +
              (1.f - al) * a2 * item_emb[i2 * 64 + lane];
      }
      yi_r[rr] = yi;
      tp_r[rr] = l0 * hu[r * 64 + lane] + l2 * su[r * 64 + lane];
    }
  }
  __syncthreads();

  if (w >= 4) {
    #pragma unroll
    for (int rr = 0; rr < 4; rr++) {
      const int row = (w - 4) * 4 + rr;
      const int r = r0 + row;
      float t = tp_r[rr] + l1 * huis[row][lane] + l3 * suis[row][lane];
      float Sv = t * yi_r[rr];
      #pragma unroll
      for (int off = 1; off < 64; off <<= 1) Sv += __shfl_xor(Sv, off, 64);
      if (lane == 0) out[r] = fast_sigmoid(Sv);
    }
  }
}

// ---------------------------------------------------------------------------
extern "C" void kernel_launch(void* const* d_in, const int* in_sizes, int n_in,
                              void* d_out, int out_size, void* d_ws, size_t ws_size,
                              hipStream_t stream) {
  const int*   users        = (const int*)d_in[0];
  const int*   items        = (const int*)d_in[1];
  const int*   u_items      = (const int*)d_in[2];
  const int*   u_items_mask = (const int*)d_in[3];
  const int*   u_frids      = (const int*)d_in[4];
  const int*   u_frids_mask = (const int*)d_in[5];
  const int*   u_frids_items= (const int*)d_in[6];
  const int*   F_i          = (const int*)d_in[7];
  const float* user_emb     = (const float*)d_in[8];
  const float* item_emb     = (const float*)d_in[9];
  const float* i_class      = (const float*)d_in[10];
  const float* W1  = (const float*)d_in[11]; const float* b1  = (const float*)d_in[12];
  const float* Wih = (const float*)d_in[13]; const float* Whh = (const float*)d_in[14];
  const float* bih = (const float*)d_in[15]; const float* bhh = (const float*)d_in[16];
  const float* W2  = (const float*)d_in[17]; const float* b2  = (const float*)d_in[18];
  const float* W3  = (const float*)d_in[19]; const float* b3  = (const float*)d_in[20];
  const float* W4  = (const float*)d_in[21]; const float* b4  = (const float*)d_in[22];
  const float* W5  = (const float*)d_in[23]; const float* b5  = (const float*)d_in[24];
  const float* W6  = (const float*)d_in[25]; const float* b6  = (const float*)d_in[26];
  const float* alpha   = (const float*)d_in[27];
  const float* lambdas = (const float*)d_in[28];
  float* out = (float*)d_out;

  char* ws = (char*)d_ws;
  unsigned short* ju_all = (unsigned short*)(ws + 0);         // 6,400,128 B (bf16)
  unsigned short* jv_all = (unsigned short*)(ws + 6400512);   // 6,400,128 B (bf16)
  float* hu     = (float*)(ws + 12801024);     // 1,048,576 B
  float* su     = (float*)(ws + 13849600);     // 1,048,576 B
  float* s12T   = (float*)(ws + 14898176);     // 327,680 B
  float* stats  = (float*)(ws + 15225856);     // 160 B
  float* auv    = (float*)(ws + 15226112);     // 163,840 B
  unsigned short* gxi = (unsigned short*)(ws + 15389952);     // 25,600,512 B (bf16)

  k_item_dots<<<2048, 256, 0, stream>>>(item_emb, i_class, W1, b1, W3, b3, Wih, bih, bhh,
                                        ju_all, jv_all, gxi,
                                        users, u_frids, u_frids_mask, user_emb, W4, b4,
                                        items, F_i, W6, b6, auv, s12T);
  k_lstm_pv<<<1300, 256, 0, stream>>>(gxi, u_items, u_items_mask, Whh, hu,
                                      u_frids_items, jv_all, auv, su, s12T, stats);
  k_fuse_final<<<256, 512, 0, stream>>>(hu, su, items, item_emb, W2, b2, W5, b5,
                                        F_i, s12T, stats, alpha, lambdas, out);
}

// Round 9
// 202.194 us; speedup vs baseline: 1.1712x; 1.1712x over previous
//
#include <hip/hip_runtime.h>

#define BSZ   4096
#define LSEQ  50
#define KFR   10
#define LI    20
#define DIM   64
#define NITEM 50001   // NI+1
#define CCLS  10

typedef __attribute__((ext_vector_type(8))) short short8;
typedef __attribute__((ext_vector_type(4))) float floatx4;

#define LOG2E 1.442695040888963f

__device__ inline unsigned short f2bf(float f) {
  unsigned u = __builtin_bit_cast(unsigned, f);
  u += 0x7FFF + ((u >> 16) & 1);
  return (unsigned short)(u >> 16);
}
__device__ inline float bf2f(unsigned short u) {
  return __builtin_bit_cast(float, ((unsigned)u) << 16);
}
__device__ inline float fast_exp(float x) {
  return __builtin_amdgcn_exp2f(x * LOG2E);
}
__device__ inline float fast_sigmoid(float x) {
  float e = __builtin_amdgcn_exp2f(-LOG2E * x);
  return __builtin_amdgcn_rcpf(1.0f + e);
}
__device__ inline float fast_tanh(float x) {
  float e = __builtin_amdgcn_exp2f(2.0f * LOG2E * x);
  return 1.0f - 2.0f * __builtin_amdgcn_rcpf(e + 1.0f);
}

// ---------------------------------------------------------------------------
// item_transform body (MFMA). nblk = number of blocks assigned to this body.
// ---------------------------------------------------------------------------
__device__ __forceinline__ void item_block(int bid, int nblk,
                                 const float* __restrict__ item_emb,
                                 const float* __restrict__ i_class,
                                 const float* __restrict__ W1, const float* __restrict__ b1,
                                 const float* __restrict__ W3, const float* __restrict__ b3,
                                 unsigned short* __restrict__ ju_all,
                                 unsigned short* __restrict__ jv_all) {
  __shared__ float wcls[2][CCLS][64];
  for (int i = threadIdx.x; i < CCLS * 64; i += 256) {
    wcls[0][i >> 6][i & 63] = W1[(64 + (i >> 6)) * 64 + (i & 63)];
    wcls[1][i >> 6][i & 63] = W3[(64 + (i >> 6)) * 64 + (i & 63)];
  }
  __syncthreads();
  const int lane = threadIdx.x & 63;
  const int am = lane & 15, aq = lane >> 4;

  short8 bf[2][4][2];
  #pragma unroll
  for (int t = 0; t < 4; t++) {
    #pragma unroll
    for (int f = 0; f < 2; f++) {
      short8 v1, v3;
      #pragma unroll
      for (int j = 0; j < 8; j++) {
        int k = f * 32 + aq * 8 + j;
        int n = t * 16 + am;
        v1[j] = (short)f2bf(W1[k * 64 + n]);
        v3[j] = (short)f2bf(W3[k * 64 + n]);
      }
      bf[0][t][f] = v1; bf[1][t][f] = v3;
    }
  }
  float bias1[4], bias3[4];
  #pragma unroll
  for (int t = 0; t < 4; t++) { bias1[t] = b1[t * 16 + am]; bias3[t] = b3[t * 16 + am]; }

  const int gw = (bid * 256 + threadIdx.x) >> 6;
  const int nw = nblk * 4;
  const int ntiles = (NITEM + 15) / 16;
  for (int tile = gw; tile < ntiles; tile += nw) {
    const int r0 = tile * 16;
    const int row_a = r0 + am;
    const bool va = row_a < NITEM;
    short8 af[2];
    #pragma unroll
    for (int f = 0; f < 2; f++) {
      short8 v = {0, 0, 0, 0, 0, 0, 0, 0};
      if (va) {
        const float* p = item_emb + row_a * 64 + f * 32 + aq * 8;
        #pragma unroll
        for (int j = 0; j < 8; j++) v[j] = (short)f2bf(p[j]);
      }
      af[f] = v;
    }
    float cf = 0.f;
    if (va) {
      #pragma unroll
      for (int j = 1; j < CCLS; j++) cf += i_class[row_a * CCLS + j] * (float)j;
    }
    int ci_l = (int)(cf + 0.5f);

    floatx4 acc[2][4];
    #pragma unroll
    for (int mt = 0; mt < 2; mt++)
      #pragma unroll
      for (int t = 0; t < 4; t++) {
        floatx4 a = {0.f, 0.f, 0.f, 0.f};
        a = __builtin_amdgcn_mfma_f32_16x16x32_bf16(af[0], bf[mt][t][0], a, 0, 0, 0);
        a = __builtin_amdgcn_mfma_f32_16x16x32_bf16(af[1], bf[mt][t][1], a, 0, 0, 0);
        acc[mt][t] = a;
      }
    #pragma unroll
    for (int r = 0; r < 4; r++) {
      int row = aq * 4 + r;
      int grow = r0 + row;
      int ci = __shfl(ci_l, row, 64);
      if (grow < NITEM) {
        #pragma unroll
        for (int t = 0; t < 4; t++) {
          int n = t * 16 + am;
          ju_all[grow * 64 + n] = f2bf(acc[0][t][r] + wcls[0][ci][n] + bias1[t]);
          jv_all[grow * 64 + n] = f2bf(acc[1][t][r] + wcls[1][ci][n] + bias3[t]);
        }
      }
    }
  }
}

// ---------------------------------------------------------------------------
// social DOTS body: s1/s2 scores -> s12T, attention weights -> auv.
// ---------------------------------------------------------------------------
__device__ __forceinline__ void social_dots_block(int bid,
                         const int* __restrict__ users, const int* __restrict__ u_frids,
                         const int* __restrict__ u_frids_mask,
                         const float* __restrict__ user_emb,
                         const float* __restrict__ W4, const float* __restrict__ b4,
                         const int* __restrict__ items, const float* __restrict__ item_emb,
                         const int* __restrict__ F_i, const float* __restrict__ W6,
                         const float* __restrict__ b6,
                         float* __restrict__ auv, float* __restrict__ s12T) {
  const int b = (bid * 256 + threadIdx.x) >> 6;
  if (b >= BSZ) return;
  const int lane = threadIdx.x & 63;

  float w4a = W4[lane], w4b = W4[64 + lane];
  float w6a = W6[lane], w6b = W6[64 + lane];
  float p[32];
  p[0] = user_emb[users[b] * 64 + lane] * w4a;
  p[1] = item_emb[items[b] * 64 + lane] * w6a;
  #pragma unroll
  for (int k = 0; k < KFR; k++)
    p[2 + k] = user_emb[u_frids[b * KFR + k] * 64 + lane] * w4b;
  #pragma unroll
  for (int k = 0; k < KFR; k++) {
    p[12 + k] = item_emb[F_i[b * 2 * KFR + k] * 64 + lane] * w6b;
    p[22 + k] = item_emb[F_i[b * 2 * KFR + KFR + k] * 64 + lane] * w6b;
  }
  #pragma unroll
  for (int off = 1; off < 64; off <<= 1) {
    #pragma unroll
    for (int i = 0; i < 32; i++) p[i] += __shfl_xor(p[i], off, 64);
  }

  float du = p[0] + b4[0];
  float di = p[1] + b6[0];
  int km = u_frids_mask[b];
  float at[KFR];
  float M = -1e30f;
  #pragma unroll
  for (int k = 0; k < KFR; k++) {
    float s = p[2 + k] + du;
    at[k] = (s > 0.f) ? s : 0.01f * s;
    if (k < km) M = fmaxf(M, at[k]);
  }
  float E = 0.f;
  #pragma unroll
  for (int k = 0; k < KFR; k++) {
    at[k] = (k < km) ? fast_exp(at[k] - M) : 0.f;
    E += at[k];
  }
  float scale = __builtin_amdgcn_rcpf(E) * __builtin_amdgcn_rcpf((float)km);
  if (lane == 0) {
    #pragma unroll
    for (int k = 0; k < KFR; k++) {
      auv[b * KFR + k] = at[k] * scale;
      float r1 = p[12 + k] + di; r1 = (r1 > 0.f) ? r1 : 0.01f * r1;
      float r2 = p[22 + k] + di; r2 = (r2 > 0.f) ? r2 : 0.01f * r2;
      s12T[k * BSZ + b] = r1;
      s12T[(KFR + k) * BSZ + b] = r2;
    }
  }
}

// ---------------------------------------------------------------------------
// D1 kernel: blocks 0..511 item_transform; 512..1535 social dots.
// ---------------------------------------------------------------------------
__launch_bounds__(256, 1)
__global__ void k_item_dots(const float* __restrict__ item_emb,
                            const float* __restrict__ i_class,
                            const float* __restrict__ W1, const float* __restrict__ b1,
                            const float* __restrict__ W3, const float* __restrict__ b3,
                            unsigned short* __restrict__ ju_all,
                            unsigned short* __restrict__ jv_all,
                            const int* __restrict__ users, const int* __restrict__ u_frids,
                            const int* __restrict__ u_frids_mask,
                            const float* __restrict__ user_emb,
                            const float* __restrict__ W4, const float* __restrict__ b4,
                            const int* __restrict__ items,
                            const int* __restrict__ F_i, const float* __restrict__ W6,
                            const float* __restrict__ b6,
                            float* __restrict__ auv, float* __restrict__ s12T) {
  if (blockIdx.x < 512) {
    item_block(blockIdx.x, 512, item_emb, i_class, W1, b1, W3, b3, ju_all, jv_all);
  } else {
    social_dots_block(blockIdx.x - 512, users, u_frids, u_frids_mask, user_emb, W4, b4,
                      items, item_emb, F_i, W6, b6, auv, s12T);
  }
}

// ---------------------------------------------------------------------------
// LSTM block body — R4-exact structure (proven best: 53.7 us, 0 conflicts)
// + two local tweaks:
//   (1) s_setprio(1) across step compute, (0) before the barrier — reclaims
//       issue slots from co-resident PV waves during the overlap window.
//   (2) hu-store hoisted out of the loop (register capture via cndmask).
// ---------------------------------------------------------------------------
__device__ __forceinline__ void lstm_block(int bid,
                       const unsigned short* __restrict__ ju_all,
                       const int* __restrict__ u_items,
                       const int* __restrict__ u_items_mask,
                       const float* __restrict__ Wih, const float* __restrict__ Whh,
                       const float* __restrict__ bih, const float* __restrict__ bhh,
                       float* __restrict__ hu) {
  __shared__ __attribute__((aligned(16))) unsigned short xh[2][16 * 128];
  __shared__ int uidx[16][LSEQ];

  const int tid = threadIdx.x;
  const int lane = tid & 63;
  const int w = tid >> 6;
  const int b0 = bid * 16;
  const int am = lane & 15;
  const int aq = lane >> 4;
  const int dcol = w * 16 + am;

  short8 bfrag[4][4];
  #pragma unroll
  for (int g = 0; g < 4; g++) {
    const int ncol = g * 64 + dcol;
    #pragma unroll
    for (int f = 0; f < 4; f++) {
      short8 vv;
      #pragma unroll
      for (int j = 0; j < 8; j++) {
        int k = f * 32 + aq * 8 + j;
        float wv = (k < 64) ? Wih[k * 256 + ncol]
                            : Whh[(k - 64) * 256 + ncol];
        vv[j] = (short)f2bf(wv);
      }
      bfrag[g][f] = vv;
    }
  }
  for (int idx = tid; idx < 16 * LSEQ; idx += 256) {
    int m = idx / LSEQ, l = idx % LSEQ;
    uidx[m][l] = u_items[(b0 + m) * LSEQ + l];
  }
  __syncthreads();

  float bs[4];
  #pragma unroll
  for (int g = 0; g < 4; g++) bs[g] = bih[g * 64 + dcol] + bhh[g * 64 + dcol];
  float cst[4] = {0.f, 0.f, 0.f, 0.f};
  float hreg[4] = {0.f, 0.f, 0.f, 0.f};
  int maskr[4];
  #pragma unroll
  for (int r = 0; r < 4; r++) maskr[r] = u_items_mask[b0 + aq * 4 + r];

  {
    const int j = lane;
    #pragma unroll
    for (int i = 0; i < 4; i++) {
      int m = w + i * 4;
      xh[0][m * 128 + (((j >> 3) ^ m) << 3) + (j & 7)] = ju_all[uidx[m][0] * 64 + j];
      int k = 64 + j;
      xh[0][m * 128 + (((k >> 3) ^ m) << 3) + (k & 7)] = 0;
    }
  }
  __syncthreads();

  #pragma unroll 1
  for (int l = 0; l < LSEQ; l++) {
    __builtin_amdgcn_s_setprio(1);
    const int p = l & 1, q = 1 - p;
    unsigned short xw[4];
    if (l < LSEQ - 1) {
      #pragma unroll
      for (int i = 0; i < 4; i++)
        xw[i] = ju_all[uidx[w + i * 4][l + 1] * 64 + lane];
    }
    short8 af[4];
    #pragma unroll
    for (int f = 0; f < 4; f++) {
      int chunk = (4 * f + aq) ^ am;
      af[f] = *(const short8*)&xh[p][am * 128 + chunk * 8];
    }
    floatx4 acc[4];
    #pragma unroll
    for (int g = 0; g < 4; g++) {
      floatx4 a = {0.f, 0.f, 0.f, 0.f};
      #pragma unroll
      for (int f = 0; f < 4; f++)
        a = __builtin_amdgcn_mfma_f32_16x16x32_bf16(af[f], bfrag[g][f], a, 0, 0, 0);
      acc[g] = a;
    }
    const int kcol = 64 + dcol;
    #pragma unroll
    for (int r = 0; r < 4; r++) {
      float gi = acc[0][r] + bs[0];
      float gf = acc[1][r] + bs[1];
      float gg = acc[2][r] + bs[2];
      float go = acc[3][r] + bs[3];
      float c = fast_sigmoid(gf) * cst[r] + fast_sigmoid(gi) * fast_tanh(gg);
      cst[r] = c;
      float h = fast_sigmoid(go) * fast_tanh(c);
      int m = aq * 4 + r;
      hreg[r] = (l == maskr[r] - 1) ? h : hreg[r];   // capture, store after loop
      xh[q][m * 128 + (((kcol >> 3) ^ m) << 3) + (kcol & 7)] = f2bf(h);
    }
    if (l < LSEQ - 1) {
      const int j = lane;
      #pragma unroll
      for (int i = 0; i < 4; i++) {
        int m = w + i * 4;
        xh[q][m * 128 + (((j >> 3) ^ m) << 3) + (j & 7)] = xw[i];
      }
    }
    __builtin_amdgcn_s_setprio(0);
    __syncthreads();
  }

  #pragma unroll
  for (int r = 0; r < 4; r++) {
    int m = aq * 4 + r;
    hu[(b0 + m) * 64 + dcol] = hreg[r];
  }
}

// ---------------------------------------------------------------------------
// social PV body: gather 200 jv rows, weighted-sum with precomputed auv -> su.
// ---------------------------------------------------------------------------
__device__ __forceinline__ void social_pv_block(int bid,
                         const int* __restrict__ u_frids_items,
                         const unsigned short* __restrict__ jv_all,
                         const float* __restrict__ auv,
                         float* __restrict__ su) {
  const int b = (bid * 256 + threadIdx.x) >> 6;
  if (b >= BSZ) return;
  const int lane = threadIdx.x & 63;

  const int* fit = u_frids_items + b * (KFR * LI);
  int idx0 = fit[lane];
  int idx1 = fit[64 + lane];
  int idx2 = fit[128 + lane];
  int idx3 = (lane < 8) ? fit[192 + lane] : 0;

  float s = 0.f;
  #pragma unroll
  for (int k = 0; k < KFR; k++) {
    float a = auv[b * KFR + k];
    float pk = 0.f;
    #pragma unroll
    for (int li = 0; li < LI; li++) {
      int j = k * LI + li;
      int idx;
      if (j < 64)       idx = __shfl(idx0, j, 64);
      else if (j < 128) idx = __shfl(idx1, j - 64, 64);
      else if (j < 192) idx = __shfl(idx2, j - 128, 64);
      else              idx = __shfl(idx3, j - 192, 64);
      pk += bf2f(jv_all[idx * 64 + lane]);
    }
    s = fmaf(a, pk, s);
  }
  su[b * 64 + lane] = s;
}

// ---------------------------------------------------------------------------
// colstats body: softmax stats for one column.
// ---------------------------------------------------------------------------
__device__ __forceinline__ void colstats_block(int c,
                         const float* __restrict__ s12T, float* __restrict__ stats) {
  __shared__ float red[256];
  const float* col = s12T + c * BSZ;
  float m = -1e30f;
  for (int b = threadIdx.x; b < BSZ; b += 256) m = fmaxf(m, col[b]);
  red[threadIdx.x] = m;
  __syncthreads();
  for (int s = 128; s > 0; s >>= 1) {
    if (threadIdx.x < s) red[threadIdx.x] = fmaxf(red[threadIdx.x], red[threadIdx.x + s]);
    __syncthreads();
  }
  float M = red[0];
  __syncthreads();
  float e = 0.f;
  for (int b = threadIdx.x; b < BSZ; b += 256) e += fast_exp(col[b] - M);
  red[threadIdx.x] = e;
  __syncthreads();
  for (int s = 128; s > 0; s >>= 1) {
    if (threadIdx.x < s) red[threadIdx.x] += red[threadIdx.x + s];
    __syncthreads();
  }
  if (threadIdx.x == 0) { stats[c] = M; stats[20 + c] = red[0]; }
}

// ---------------------------------------------------------------------------
// D2 kernel: blocks 0..255 LSTM; 256..1279 social pv; 1280..1299 colstats.
// ---------------------------------------------------------------------------
__launch_bounds__(256, 1)
__global__ void k_lstm_pv(const unsigned short* __restrict__ ju_all,
                          const int* __restrict__ u_items,
                          const int* __restrict__ u_items_mask,
                          const float* __restrict__ Wih, const float* __restrict__ Whh,
                          const float* __restrict__ bih, const float* __restrict__ bhh,
                          float* __restrict__ hu,
                          const int* __restrict__ u_frids_items,
                          const unsigned short* __restrict__ jv_all,
                          const float* __restrict__ auv, float* __restrict__ su,
                          const float* __restrict__ s12T, float* __restrict__ stats) {
  if (blockIdx.x < 256) {
    lstm_block(blockIdx.x, ju_all, u_items, u_items_mask, Wih, Whh, bih, bhh, hu);
  } else if (blockIdx.x < 1280) {
    social_pv_block(blockIdx.x - 256, u_frids_items, jv_all, auv, su);
  } else {
    colstats_block(blockIdx.x - 1280, s12T, stats);
  }
}

// ---------------------------------------------------------------------------
// D3 (MFMA): hui/sui GEMMs + final epilogue, 16-row tiles, GEMM/gather
// wave split (waves 0-3 GEMM, waves 4-7 yi gather concurrently).
// ---------------------------------------------------------------------------
__launch_bounds__(512, 1)
__global__ void k_fuse_final(const float* __restrict__ hu, const float* __restrict__ su,
                             const int* __restrict__ items,
                             const float* __restrict__ item_emb,
                             const float* __restrict__ W2, const float* __restrict__ b2,
                             const float* __restrict__ W5, const float* __restrict__ b5,
                             const int* __restrict__ F_i,
                             const float* __restrict__ s12T, const float* __restrict__ stats,
                             const float* __restrict__ alpha, const float* __restrict__ lambdas,
                             float* __restrict__ out) {
  __shared__ float huis[16][66];
  __shared__ float suis[16][66];

  const int lane = threadIdx.x & 63;
  const int w = threadIdx.x >> 6;      // 0..7
  const int r0 = blockIdx.x * 16;

  const float al = alpha[0];
  const float l0 = lambdas[0], l1 = lambdas[1], l2 = lambdas[2], l3 = lambdas[3];

  float yi_r[4];
  float tp_r[4];

  if (w < 4) {
    const int mat = w >> 1;
    const int half = w & 1;
    const int am = lane & 15, aq = lane >> 4;

    const float* W = mat ? W5 : W2;
    const float* bb = mat ? b5 : b2;
    const float* xsrc = mat ? su : hu;

    short8 bfr[6][2];
    #pragma unroll
    for (int f = 0; f < 6; f++) {
      #pragma unroll
      for (int t = 0; t < 2; t++) {
        const int n = half * 32 + t * 16 + am;
        short8 v;
        #pragma unroll
        for (int j = 0; j < 8; j++) {
          int k = f * 32 + aq * 8 + j;
          v[j] = (short)f2bf(W[k * 64 + n]);
        }
        bfr[f][t] = v;
      }
    }
    float bias[2];
    #pragma unroll
    for (int t = 0; t < 2; t++) bias[t] = bb[half * 32 + t * 16 + am];

    const int row_a = r0 + am;
    const int it = items[row_a];
    short8 af[6];
    #pragma unroll
    for (int c = 0; c < 2; c++) {
      short8 vx, ve, vp;
      const float* xp = xsrc + row_a * 64 + c * 32 + aq * 8;
      const float* ep = item_emb + it * 64 + c * 32 + aq * 8;
      #pragma unroll
      for (int j = 0; j < 8; j++) {
        float x = xp[j], e = ep[j];
        vx[j] = (short)f2bf(x);
        ve[j] = (short)f2bf(e);
        vp[j] = (short)f2bf(x * e);
      }
      af[c] = vx; af[2 + c] = ve; af[4 + c] = vp;
    }
    floatx4 acc[2];
    #pragma unroll
    for (int t = 0; t < 2; t++) {
      floatx4 a = {0.f, 0.f, 0.f, 0.f};
      #pragma unroll
      for (int f = 0; f < 6; f++)
        a = __builtin_amdgcn_mfma_f32_16x16x32_bf16(af[f], bfr[f][t], a, 0, 0, 0);
      acc[t] = a;
    }
    float (*dst)[66] = mat ? suis : huis;
    #pragma unroll
    for (int t = 0; t < 2; t++)
      #pragma unroll
      for (int r = 0; r < 4; r++)
        dst[aq * 4 + r][half * 32 + t * 16 + am] = acc[t][r] + bias[t];
  } else {
    #pragma unroll
    for (int rr = 0; rr < 4; rr++) {
      const int r = r0 + (w - 4) * 4 + rr;
      float p1 = 0.f, p2 = 0.f;
      if (lane < KFR) {
        float v1 = s12T[lane * BSZ + r];
        float v2 = s12T[(KFR + lane) * BSZ + r];
        p1 = fast_exp(v1 - stats[lane]) * __builtin_amdgcn_rcpf(stats[20 + lane]);
        p2 = fast_exp(v2 - stats[KFR + lane]) * __builtin_amdgcn_rcpf(stats[30 + lane]);
      }
      float yi = 0.f;
      #pragma unroll
      for (int k = 0; k < KFR; k++) {
        float a1 = __shfl(p1, k, 64);
        float a2 = __shfl(p2, k, 64);
        int i1 = F_i[r * 2 * KFR + k];
        int i2 = F_i[r * 2 * KFR + KFR + k];
        yi += al * a1 * item_emb[i1 * 64 + lane] +
              (1.f - al) * a2 * item_emb[i2 * 64 + lane];
      }
      yi_r[rr] = yi;
      tp_r[rr] = l0 * hu[r * 64 + lane] + l2 * su[r * 64 + lane];
    }
  }
  __syncthreads();

  if (w >= 4) {
    #pragma unroll
    for (int rr = 0; rr < 4; rr++) {
      const int row = (w - 4) * 4 + rr;
      const int r = r0 + row;
      float t = tp_r[rr] + l1 * huis[row][lane] + l3 * suis[row][lane];
      float Sv = t * yi_r[rr];
      #pragma unroll
      for (int off = 1; off < 64; off <<= 1) Sv += __shfl_xor(Sv, off, 64);
      if (lane == 0) out[r] = fast_sigmoid(Sv);
    }
  }
}

// ---------------------------------------------------------------------------
extern "C" void kernel_launch(void* const* d_in, const int* in_sizes, int n_in,
                              void* d_out, int out_size, void* d_ws, size_t ws_size,
                              hipStream_t stream) {
  const int*   users        = (const int*)d_in[0];
  const int*   items        = (const int*)d_in[1];
  const int*   u_items      = (const int*)d_in[2];
  const int*   u_items_mask = (const int*)d_in[3];
  const int*   u_frids      = (const int*)d_in[4];
  const int*   u_frids_mask = (const int*)d_in[5];
  const int*   u_frids_items= (const int*)d_in[6];
  const int*   F_i          = (const int*)d_in[7];
  const float* user_emb     = (const float*)d_in[8];
  const float* item_emb     = (const float*)d_in[9];
  const float* i_class      = (const float*)d_in[10];
  const float* W1  = (const float*)d_in[11]; const float* b1  = (const float*)d_in[12];
  const float* Wih = (const float*)d_in[13]; const float* Whh = (const float*)d_in[14];
  const float* bih = (const float*)d_in[15]; const float* bhh = (const float*)d_in[16];
  const float* W2  = (const float*)d_in[17]; const float* b2  = (const float*)d_in[18];
  const float* W3  = (const float*)d_in[19]; const float* b3  = (const float*)d_in[20];
  const float* W4  = (const float*)d_in[21]; const float* b4  = (const float*)d_in[22];
  const float* W5  = (const float*)d_in[23]; const float* b5  = (const float*)d_in[24];
  const float* W6  = (const float*)d_in[25]; const float* b6  = (const float*)d_in[26];
  const float* alpha   = (const float*)d_in[27];
  const float* lambdas = (const float*)d_in[28];
  float* out = (float*)d_out;

  char* ws = (char*)d_ws;
  unsigned short* ju_all = (unsigned short*)(ws + 0);         // 6,400,128 B (bf16)
  unsigned short* jv_all = (unsigned short*)(ws + 6400512);   // 6,400,128 B (bf16)
  float* hu     = (float*)(ws + 12801024);     // 1,048,576 B
  float* su     = (float*)(ws + 13849600);     // 1,048,576 B
  float* s12T   = (float*)(ws + 14898176);     // 327,680 B
  float* stats  = (float*)(ws + 15225856);     // 160 B
  float* auv    = (float*)(ws + 15226112);     // 163,840 B

  k_item_dots<<<1536, 256, 0, stream>>>(item_emb, i_class, W1, b1, W3, b3, ju_all, jv_all,
                                        users, u_frids, u_frids_mask, user_emb, W4, b4,
                                        items, F_i, W6, b6, auv, s12T);
  k_lstm_pv<<<1300, 256, 0, stream>>>(ju_all, u_items, u_items_mask, Wih, Whh, bih, bhh, hu,
                                      u_frids_items, jv_all, auv, su, s12T, stats);
  k_fuse_final<<<256, 512, 0, stream>>>(hu, su, items, item_emb, W2, b2, W5, b5,
                                        F_i, s12T, stats, alpha, lambdas, out);
}

// Round 10
// 200.259 us; speedup vs baseline: 1.1826x; 1.0097x over previous
//
#include <hip/hip_runtime.h>

#define BSZ   4096
#define LSEQ  50
#define KFR   10
#define LI    20
#define DIM   64
#define NITEM 50001   // NI+1
#define CCLS  10

typedef __attribute__((ext_vector_type(8))) short short8;
typedef __attribute__((ext_vector_type(4))) float floatx4;

#define LOG2E 1.442695040888963f

__device__ inline unsigned short f2bf(float f) {
  unsigned u = __builtin_bit_cast(unsigned, f);
  u += 0x7FFF + ((u >> 16) & 1);
  return (unsigned short)(u >> 16);
}
__device__ inline float bf2f(unsigned short u) {
  return __builtin_bit_cast(float, ((unsigned)u) << 16);
}
__device__ inline float fast_exp(float x) {
  return __builtin_amdgcn_exp2f(x * LOG2E);
}
__device__ inline float fast_sigmoid(float x) {
  float e = __builtin_amdgcn_exp2f(-LOG2E * x);
  return __builtin_amdgcn_rcpf(1.0f + e);
}
__device__ inline float fast_tanh(float x) {
  float e = __builtin_amdgcn_exp2f(2.0f * LOG2E * x);
  return 1.0f - 2.0f * __builtin_amdgcn_rcpf(e + 1.0f);
}

// ---------------------------------------------------------------------------
// item_transform body (MFMA). nblk = number of blocks assigned to this body.
// 768 blocks: 3126 tiles / 3072 waves = 1.02 tiles/wave (was 1.53 at 512).
// ---------------------------------------------------------------------------
__device__ __forceinline__ void item_block(int bid, int nblk,
                                 const float* __restrict__ item_emb,
                                 const float* __restrict__ i_class,
                                 const float* __restrict__ W1, const float* __restrict__ b1,
                                 const float* __restrict__ W3, const float* __restrict__ b3,
                                 unsigned short* __restrict__ ju_all,
                                 unsigned short* __restrict__ jv_all) {
  __shared__ float wcls[2][CCLS][64];
  for (int i = threadIdx.x; i < CCLS * 64; i += 256) {
    wcls[0][i >> 6][i & 63] = W1[(64 + (i >> 6)) * 64 + (i & 63)];
    wcls[1][i >> 6][i & 63] = W3[(64 + (i >> 6)) * 64 + (i & 63)];
  }
  __syncthreads();
  const int lane = threadIdx.x & 63;
  const int am = lane & 15, aq = lane >> 4;

  short8 bf[2][4][2];
  #pragma unroll
  for (int t = 0; t < 4; t++) {
    #pragma unroll
    for (int f = 0; f < 2; f++) {
      short8 v1, v3;
      #pragma unroll
      for (int j = 0; j < 8; j++) {
        int k = f * 32 + aq * 8 + j;
        int n = t * 16 + am;
        v1[j] = (short)f2bf(W1[k * 64 + n]);
        v3[j] = (short)f2bf(W3[k * 64 + n]);
      }
      bf[0][t][f] = v1; bf[1][t][f] = v3;
    }
  }
  float bias1[4], bias3[4];
  #pragma unroll
  for (int t = 0; t < 4; t++) { bias1[t] = b1[t * 16 + am]; bias3[t] = b3[t * 16 + am]; }

  const int gw = (bid * 256 + threadIdx.x) >> 6;
  const int nw = nblk * 4;
  const int ntiles = (NITEM + 15) / 16;
  for (int tile = gw; tile < ntiles; tile += nw) {
    const int r0 = tile * 16;
    const int row_a = r0 + am;
    const bool va = row_a < NITEM;
    short8 af[2];
    #pragma unroll
    for (int f = 0; f < 2; f++) {
      short8 v = {0, 0, 0, 0, 0, 0, 0, 0};
      if (va) {
        const float* p = item_emb + row_a * 64 + f * 32 + aq * 8;
        #pragma unroll
        for (int j = 0; j < 8; j++) v[j] = (short)f2bf(p[j]);
      }
      af[f] = v;
    }
    float cf = 0.f;
    if (va) {
      #pragma unroll
      for (int j = 1; j < CCLS; j++) cf += i_class[row_a * CCLS + j] * (float)j;
    }
    int ci_l = (int)(cf + 0.5f);

    floatx4 acc[2][4];
    #pragma unroll
    for (int mt = 0; mt < 2; mt++)
      #pragma unroll
      for (int t = 0; t < 4; t++) {
        floatx4 a = {0.f, 0.f, 0.f, 0.f};
        a = __builtin_amdgcn_mfma_f32_16x16x32_bf16(af[0], bf[mt][t][0], a, 0, 0, 0);
        a = __builtin_amdgcn_mfma_f32_16x16x32_bf16(af[1], bf[mt][t][1], a, 0, 0, 0);
        acc[mt][t] = a;
      }
    #pragma unroll
    for (int r = 0; r < 4; r++) {
      int row = aq * 4 + r;
      int grow = r0 + row;
      int ci = __shfl(ci_l, row, 64);
      if (grow < NITEM) {
        #pragma unroll
        for (int t = 0; t < 4; t++) {
          int n = t * 16 + am;
          ju_all[grow * 64 + n] = f2bf(acc[0][t][r] + wcls[0][ci][n] + bias1[t]);
          jv_all[grow * 64 + n] = f2bf(acc[1][t][r] + wcls[1][ci][n] + bias3[t]);
        }
      }
    }
  }
}

// ---------------------------------------------------------------------------
// social DOTS body: s1/s2 scores -> s12T, attention weights -> auv.
// ---------------------------------------------------------------------------
__device__ __forceinline__ void social_dots_block(int bid,
                         const int* __restrict__ users, const int* __restrict__ u_frids,
                         const int* __restrict__ u_frids_mask,
                         const float* __restrict__ user_emb,
                         const float* __restrict__ W4, const float* __restrict__ b4,
                         const int* __restrict__ items, const float* __restrict__ item_emb,
                         const int* __restrict__ F_i, const float* __restrict__ W6,
                         const float* __restrict__ b6,
                         float* __restrict__ auv, float* __restrict__ s12T) {
  const int b = (bid * 256 + threadIdx.x) >> 6;
  if (b >= BSZ) return;
  const int lane = threadIdx.x & 63;

  float w4a = W4[lane], w4b = W4[64 + lane];
  float w6a = W6[lane], w6b = W6[64 + lane];
  float p[32];
  p[0] = user_emb[users[b] * 64 + lane] * w4a;
  p[1] = item_emb[items[b] * 64 + lane] * w6a;
  #pragma unroll
  for (int k = 0; k < KFR; k++)
    p[2 + k] = user_emb[u_frids[b * KFR + k] * 64 + lane] * w4b;
  #pragma unroll
  for (int k = 0; k < KFR; k++) {
    p[12 + k] = item_emb[F_i[b * 2 * KFR + k] * 64 + lane] * w6b;
    p[22 + k] = item_emb[F_i[b * 2 * KFR + KFR + k] * 64 + lane] * w6b;
  }
  #pragma unroll
  for (int off = 1; off < 64; off <<= 1) {
    #pragma unroll
    for (int i = 0; i < 32; i++) p[i] += __shfl_xor(p[i], off, 64);
  }

  float du = p[0] + b4[0];
  float di = p[1] + b6[0];
  int km = u_frids_mask[b];
  float at[KFR];
  float M = -1e30f;
  #pragma unroll
  for (int k = 0; k < KFR; k++) {
    float s = p[2 + k] + du;
    at[k] = (s > 0.f) ? s : 0.01f * s;
    if (k < km) M = fmaxf(M, at[k]);
  }
  float E = 0.f;
  #pragma unroll
  for (int k = 0; k < KFR; k++) {
    at[k] = (k < km) ? fast_exp(at[k] - M) : 0.f;
    E += at[k];
  }
  float scale = __builtin_amdgcn_rcpf(E) * __builtin_amdgcn_rcpf((float)km);
  if (lane == 0) {
    #pragma unroll
    for (int k = 0; k < KFR; k++) {
      auv[b * KFR + k] = at[k] * scale;
      float r1 = p[12 + k] + di; r1 = (r1 > 0.f) ? r1 : 0.01f * r1;
      float r2 = p[22 + k] + di; r2 = (r2 > 0.f) ? r2 : 0.01f * r2;
      s12T[k * BSZ + b] = r1;
      s12T[(KFR + k) * BSZ + b] = r2;
    }
  }
}

// ---------------------------------------------------------------------------
// D1 kernel: blocks 0..767 item_transform; 768..1791 social dots.
// ---------------------------------------------------------------------------
__launch_bounds__(256, 1)
__global__ void k_item_dots(const float* __restrict__ item_emb,
                            const float* __restrict__ i_class,
                            const float* __restrict__ W1, const float* __restrict__ b1,
                            const float* __restrict__ W3, const float* __restrict__ b3,
                            unsigned short* __restrict__ ju_all,
                            unsigned short* __restrict__ jv_all,
                            const int* __restrict__ users, const int* __restrict__ u_frids,
                            const int* __restrict__ u_frids_mask,
                            const float* __restrict__ user_emb,
                            const float* __restrict__ W4, const float* __restrict__ b4,
                            const int* __restrict__ items,
                            const int* __restrict__ F_i, const float* __restrict__ W6,
                            const float* __restrict__ b6,
                            float* __restrict__ auv, float* __restrict__ s12T) {
  if (blockIdx.x < 768) {
    item_block(blockIdx.x, 768, item_emb, i_class, W1, b1, W3, b3, ju_all, jv_all);
  } else {
    social_dots_block(blockIdx.x - 768, users, u_frids, u_frids_mask, user_emb, W4, b4,
                      items, item_emb, F_i, W6, b6, auv, s12T);
  }
}

// ---------------------------------------------------------------------------
// LSTM block body — R4-exact structure + R9 tweaks (proven: 48.9 us), with
// setprio raised 1 -> 3 (stronger issue arbitration vs co-resident PV waves).
// ---------------------------------------------------------------------------
__device__ __forceinline__ void lstm_block(int bid,
                       const unsigned short* __restrict__ ju_all,
                       const int* __restrict__ u_items,
                       const int* __restrict__ u_items_mask,
                       const float* __restrict__ Wih, const float* __restrict__ Whh,
                       const float* __restrict__ bih, const float* __restrict__ bhh,
                       float* __restrict__ hu) {
  __shared__ __attribute__((aligned(16))) unsigned short xh[2][16 * 128];
  __shared__ int uidx[16][LSEQ];

  const int tid = threadIdx.x;
  const int lane = tid & 63;
  const int w = tid >> 6;
  const int b0 = bid * 16;
  const int am = lane & 15;
  const int aq = lane >> 4;
  const int dcol = w * 16 + am;

  short8 bfrag[4][4];
  #pragma unroll
  for (int g = 0; g < 4; g++) {
    const int ncol = g * 64 + dcol;
    #pragma unroll
    for (int f = 0; f < 4; f++) {
      short8 vv;
      #pragma unroll
      for (int j = 0; j < 8; j++) {
        int k = f * 32 + aq * 8 + j;
        float wv = (k < 64) ? Wih[k * 256 + ncol]
                            : Whh[(k - 64) * 256 + ncol];
        vv[j] = (short)f2bf(wv);
      }
      bfrag[g][f] = vv;
    }
  }
  for (int idx = tid; idx < 16 * LSEQ; idx += 256) {
    int m = idx / LSEQ, l = idx % LSEQ;
    uidx[m][l] = u_items[(b0 + m) * LSEQ + l];
  }
  __syncthreads();

  float bs[4];
  #pragma unroll
  for (int g = 0; g < 4; g++) bs[g] = bih[g * 64 + dcol] + bhh[g * 64 + dcol];
  float cst[4] = {0.f, 0.f, 0.f, 0.f};
  float hreg[4] = {0.f, 0.f, 0.f, 0.f};
  int maskr[4];
  #pragma unroll
  for (int r = 0; r < 4; r++) maskr[r] = u_items_mask[b0 + aq * 4 + r];

  {
    const int j = lane;
    #pragma unroll
    for (int i = 0; i < 4; i++) {
      int m = w + i * 4;
      xh[0][m * 128 + (((j >> 3) ^ m) << 3) + (j & 7)] = ju_all[uidx[m][0] * 64 + j];
      int k = 64 + j;
      xh[0][m * 128 + (((k >> 3) ^ m) << 3) + (k & 7)] = 0;
    }
  }
  __syncthreads();

  #pragma unroll 1
  for (int l = 0; l < LSEQ; l++) {
    __builtin_amdgcn_s_setprio(3);
    const int p = l & 1, q = 1 - p;
    unsigned short xw[4];
    if (l < LSEQ - 1) {
      #pragma unroll
      for (int i = 0; i < 4; i++)
        xw[i] = ju_all[uidx[w + i * 4][l + 1] * 64 + lane];
    }
    short8 af[4];
    #pragma unroll
    for (int f = 0; f < 4; f++) {
      int chunk = (4 * f + aq) ^ am;
      af[f] = *(const short8*)&xh[p][am * 128 + chunk * 8];
    }
    floatx4 acc[4];
    #pragma unroll
    for (int g = 0; g < 4; g++) {
      floatx4 a = {0.f, 0.f, 0.f, 0.f};
      #pragma unroll
      for (int f = 0; f < 4; f++)
        a = __builtin_amdgcn_mfma_f32_16x16x32_bf16(af[f], bfrag[g][f], a, 0, 0, 0);
      acc[g] = a;
    }
    const int kcol = 64 + dcol;
    #pragma unroll
    for (int r = 0; r < 4; r++) {
      float gi = acc[0][r] + bs[0];
      float gf = acc[1][r] + bs[1];
      float gg = acc[2][r] + bs[2];
      float go = acc[3][r] + bs[3];
      float c = fast_sigmoid(gf) * cst[r] + fast_sigmoid(gi) * fast_tanh(gg);
      cst[r] = c;
      float h = fast_sigmoid(go) * fast_tanh(c);
      int m = aq * 4 + r;
      hreg[r] = (l == maskr[r] - 1) ? h : hreg[r];   // capture, store after loop
      xh[q][m * 128 + (((kcol >> 3) ^ m) << 3) + (kcol & 7)] = f2bf(h);
    }
    if (l < LSEQ - 1) {
      const int j = lane;
      #pragma unroll
      for (int i = 0; i < 4; i++) {
        int m = w + i * 4;
        xh[q][m * 128 + (((j >> 3) ^ m) << 3) + (j & 7)] = xw[i];
      }
    }
    __builtin_amdgcn_s_setprio(0);
    __syncthreads();
  }

  #pragma unroll
  for (int r = 0; r < 4; r++) {
    int m = aq * 4 + r;
    hu[(b0 + m) * 64 + dcol] = hreg[r];
  }
}

// ---------------------------------------------------------------------------
// social PV body: gather 200 jv rows, weighted-sum with precomputed auv -> su.
// ---------------------------------------------------------------------------
__device__ __forceinline__ void social_pv_block(int bid,
                         const int* __restrict__ u_frids_items,
                         const unsigned short* __restrict__ jv_all,
                         const float* __restrict__ auv,
                         float* __restrict__ su) {
  const int b = (bid * 256 + threadIdx.x) >> 6;
  if (b >= BSZ) return;
  const int lane = threadIdx.x & 63;

  const int* fit = u_frids_items + b * (KFR * LI);
  int idx0 = fit[lane];
  int idx1 = fit[64 + lane];
  int idx2 = fit[128 + lane];
  int idx3 = (lane < 8) ? fit[192 + lane] : 0;

  float s = 0.f;
  #pragma unroll
  for (int k = 0; k < KFR; k++) {
    float a = auv[b * KFR + k];
    float pk = 0.f;
    #pragma unroll
    for (int li = 0; li < LI; li++) {
      int j = k * LI + li;
      int idx;
      if (j < 64)       idx = __shfl(idx0, j, 64);
      else if (j < 128) idx = __shfl(idx1, j - 64, 64);
      else if (j < 192) idx = __shfl(idx2, j - 128, 64);
      else              idx = __shfl(idx3, j - 192, 64);
      pk += bf2f(jv_all[idx * 64 + lane]);
    }
    s = fmaf(a, pk, s);
  }
  su[b * 64 + lane] = s;
}

// ---------------------------------------------------------------------------
// colstats body: softmax stats for one column.
// ---------------------------------------------------------------------------
__device__ __forceinline__ void colstats_block(int c,
                         const float* __restrict__ s12T, float* __restrict__ stats) {
  __shared__ float red[256];
  const float* col = s12T + c * BSZ;
  float m = -1e30f;
  for (int b = threadIdx.x; b < BSZ; b += 256) m = fmaxf(m, col[b]);
  red[threadIdx.x] = m;
  __syncthreads();
  for (int s = 128; s > 0; s >>= 1) {
    if (threadIdx.x < s) red[threadIdx.x] = fmaxf(red[threadIdx.x], red[threadIdx.x + s]);
    __syncthreads();
  }
  float M = red[0];
  __syncthreads();
  float e = 0.f;
  for (int b = threadIdx.x; b < BSZ; b += 256) e += fast_exp(col[b] - M);
  red[threadIdx.x] = e;
  __syncthreads();
  for (int s = 128; s > 0; s >>= 1) {
    if (threadIdx.x < s) red[threadIdx.x] += red[threadIdx.x + s];
    __syncthreads();
  }
  if (threadIdx.x == 0) { stats[c] = M; stats[20 + c] = red[0]; }
}

// ---------------------------------------------------------------------------
// D2 kernel: blocks 0..255 LSTM; 256..1279 social pv; 1280..1299 colstats.
// ---------------------------------------------------------------------------
__launch_bounds__(256, 1)
__global__ void k_lstm_pv(const unsigned short* __restrict__ ju_all,
                          const int* __restrict__ u_items,
                          const int* __restrict__ u_items_mask,
                          const float* __restrict__ Wih, const float* __restrict__ Whh,
                          const float* __restrict__ bih, const float* __restrict__ bhh,
                          float* __restrict__ hu,
                          const int* __restrict__ u_frids_items,
                          const unsigned short* __restrict__ jv_all,
                          const float* __restrict__ auv, float* __restrict__ su,
                          const float* __restrict__ s12T, float* __restrict__ stats) {
  if (blockIdx.x < 256) {
    lstm_block(blockIdx.x, ju_all, u_items, u_items_mask, Wih, Whh, bih, bhh, hu);
  } else if (blockIdx.x < 1280) {
    social_pv_block(blockIdx.x - 256, u_frids_items, jv_all, auv, su);
  } else {
    colstats_block(blockIdx.x - 1280, s12T, stats);
  }
}

// ---------------------------------------------------------------------------
// D3 (MFMA): hui/sui GEMMs + final epilogue, 16-row tiles, GEMM/gather
// wave split (waves 0-3 GEMM, waves 4-7 yi gather concurrently).
// ---------------------------------------------------------------------------
__launch_bounds__(512, 1)
__global__ void k_fuse_final(const float* __restrict__ hu, const float* __restrict__ su,
                             const int* __restrict__ items,
                             const float* __restrict__ item_emb,
                             const float* __restrict__ W2, const float* __restrict__ b2,
                             const float* __restrict__ W5, const float* __restrict__ b5,
                             const int* __restrict__ F_i,
                             const float* __restrict__ s12T, const float* __restrict__ stats,
                             const float* __restrict__ alpha, const float* __restrict__ lambdas,
                             float* __restrict__ out) {
  __shared__ float huis[16][66];
  __shared__ float suis[16][66];

  const int lane = threadIdx.x & 63;
  const int w = threadIdx.x >> 6;      // 0..7
  const int r0 = blockIdx.x * 16;

  const float al = alpha[0];
  const float l0 = lambdas[0], l1 = lambdas[1], l2 = lambdas[2], l3 = lambdas[3];

  float yi_r[4];
  float tp_r[4];

  if (w < 4) {
    const int mat = w >> 1;
    const int half = w & 1;
    const int am = lane & 15, aq = lane >> 4;

    const float* W = mat ? W5 : W2;
    const float* bb = mat ? b5 : b2;
    const float* xsrc = mat ? su : hu;

    short8 bfr[6][2];
    #pragma unroll
    for (int f = 0; f < 6; f++) {
      #pragma unroll
      for (int t = 0; t < 2; t++) {
        const int n = half * 32 + t * 16 + am;
        short8 v;
        #pragma unroll
        for (int j = 0; j < 8; j++) {
          int k = f * 32 + aq * 8 + j;
          v[j] = (short)f2bf(W[k * 64 + n]);
        }
        bfr[f][t] = v;
      }
    }
    float bias[2];
    #pragma unroll
    for (int t = 0; t < 2; t++) bias[t] = bb[half * 32 + t * 16 + am];

    const int row_a = r0 + am;
    const int it = items[row_a];
    short8 af[6];
    #pragma unroll
    for (int c = 0; c < 2; c++) {
      short8 vx, ve, vp;
      const float* xp = xsrc + row_a * 64 + c * 32 + aq * 8;
      const float* ep = item_emb + it * 64 + c * 32 + aq * 8;
      #pragma unroll
      for (int j = 0; j < 8; j++) {
        float x = xp[j], e = ep[j];
        vx[j] = (short)f2bf(x);
        ve[j] = (short)f2bf(e);
        vp[j] = (short)f2bf(x * e);
      }
      af[c] = vx; af[2 + c] = ve; af[4 + c] = vp;
    }
    floatx4 acc[2];
    #pragma unroll
    for (int t = 0; t < 2; t++) {
      floatx4 a = {0.f, 0.f, 0.f, 0.f};
      #pragma unroll
      for (int f = 0; f < 6; f++)
        a = __builtin_amdgcn_mfma_f32_16x16x32_bf16(af[f], bfr[f][t], a, 0, 0, 0);
      acc[t] = a;
    }
    float (*dst)[66] = mat ? suis : huis;
    #pragma unroll
    for (int t = 0; t < 2; t++)
      #pragma unroll
      for (int r = 0; r < 4; r++)
        dst[aq * 4 + r][half * 32 + t * 16 + am] = acc[t][r] + bias[t];
  } else {
    #pragma unroll
    for (int rr = 0; rr < 4; rr++) {
      const int r = r0 + (w - 4) * 4 + rr;
      float p1 = 0.f, p2 = 0.f;
      if (lane < KFR) {
        float v1 = s12T[lane * BSZ + r];
        float v2 = s12T[(KFR + lane) * BSZ + r];
        p1 = fast_exp(v1 - stats[lane]) * __builtin_amdgcn_rcpf(stats[20 + lane]);
        p2 = fast_exp(v2 - stats[KFR + lane]) * __builtin_amdgcn_rcpf(stats[30 + lane]);
      }
      float yi = 0.f;
      #pragma unroll
      for (int k = 0; k < KFR; k++) {
        float a1 = __shfl(p1, k, 64);
        float a2 = __shfl(p2, k, 64);
        int i1 = F_i[r * 2 * KFR + k];
        int i2 = F_i[r * 2 * KFR + KFR + k];
        yi += al * a1 * item_emb[i1 * 64 + lane] +
              (1.f - al) * a2 * item_emb[i2 * 64 + lane];
      }
      yi_r[rr] = yi;
      tp_r[rr] = l0 * hu[r * 64 + lane] + l2 * su[r * 64 + lane];
    }
  }
  __syncthreads();

  if (w >= 4) {
    #pragma unroll
    for (int rr = 0; rr < 4; rr++) {
      const int row = (w - 4) * 4 + rr;
      const int r = r0 + row;
      float t = tp_r[rr] + l1 * huis[row][lane] + l3 * suis[row][lane];
      float Sv = t * yi_r[rr];
      #pragma unroll
      for (int off = 1; off < 64; off <<= 1) Sv += __shfl_xor(Sv, off, 64);
      if (lane == 0) out[r] = fast_sigmoid(Sv);
    }
  }
}

// ---------------------------------------------------------------------------
extern "C" void kernel_launch(void* const* d_in, const int* in_sizes, int n_in,
                              void* d_out, int out_size, void* d_ws, size_t ws_size,
                              hipStream_t stream) {
  const int*   users        = (const int*)d_in[0];
  const int*   items        = (const int*)d_in[1];
  const int*   u_items      = (const int*)d_in[2];
  const int*   u_items_mask = (const int*)d_in[3];
  const int*   u_frids      = (const int*)d_in[4];
  const int*   u_frids_mask = (const int*)d_in[5];
  const int*   u_frids_items= (const int*)d_in[6];
  const int*   F_i          = (const int*)d_in[7];
  const float* user_emb     = (const float*)d_in[8];
  const float* item_emb     = (const float*)d_in[9];
  const float* i_class      = (const float*)d_in[10];
  const float* W1  = (const float*)d_in[11]; const float* b1  = (const float*)d_in[12];
  const float* Wih = (const float*)d_in[13]; const float* Whh = (const float*)d_in[14];
  const float* bih = (const float*)d_in[15]; const float* bhh = (const float*)d_in[16];
  const float* W2  = (const float*)d_in[17]; const float* b2  = (const float*)d_in[18];
  const float* W3  = (const float*)d_in[19]; const float* b3  = (const float*)d_in[20];
  const float* W4  = (const float*)d_in[21]; const float* b4  = (const float*)d_in[22];
  const float* W5  = (const float*)d_in[23]; const float* b5  = (const float*)d_in[24];
  const float* W6  = (const float*)d_in[25]; const float* b6  = (const float*)d_in[26];
  const float* alpha   = (const float*)d_in[27];
  const float* lambdas = (const float*)d_in[28];
  float* out = (float*)d_out;

  char* ws = (char*)d_ws;
  unsigned short* ju_all = (unsigned short*)(ws + 0);         // 6,400,128 B (bf16)
  unsigned short* jv_all = (unsigned short*)(ws + 6400512);   // 6,400,128 B (bf16)
  float* hu     = (float*)(ws + 12801024);     // 1,048,576 B
  float* su     = (float*)(ws + 13849600);     // 1,048,576 B
  float* s12T   = (float*)(ws + 14898176);     // 327,680 B
  float* stats  = (float*)(ws + 15225856);     // 160 B
  float* auv    = (float*)(ws + 15226112);     // 163,840 B

  k_item_dots<<<1792, 256, 0, stream>>>(item_emb, i_class, W1, b1, W3, b3, ju_all, jv_all,
                                        users, u_frids, u_frids_mask, user_emb, W4, b4,
                                        items, F_i, W6, b6, auv, s12T);
  k_lstm_pv<<<1300, 256, 0, stream>>>(ju_all, u_items, u_items_mask, Wih, Whh, bih, bhh, hu,
                                      u_frids_items, jv_all, auv, su, s12T, stats);
  k_fuse_final<<<256, 512, 0, stream>>>(hu, su, items, item_emb, W2, b2, W5, b5,
                                        F_i, s12T, stats, alpha, lambdas, out);
}